// Round 3
// baseline (189.027 us; speedup 1.0000x reference)
//
#include <hip/hip_runtime.h>

#define HIDDEN 256
#define RPB 256      // rows (nodes) per block in segment-sum
#define GT 8         // graphs per block in MLP

// ---------------------------------------------------------------------------
// Segment sum over sorted batch ids.
// Block = 256 threads = 4 waves. Wave w handles rows r0+w, r0+w+4, ...
// Each lane owns 4 consecutive hidden dims (float4, 16B/lane coalesced).
// Since batch is sorted, each wave keeps a running float4 accumulator and
// flushes with atomicAdd only when the segment id changes (~2 flushes/block).
// ---------------------------------------------------------------------------
__global__ __launch_bounds__(256) void seg_sum_kernel(
    const float4* __restrict__ hv4, const int* __restrict__ batch,
    float* __restrict__ sums, float* __restrict__ counts, int n_nodes)
{
    __shared__ int sb[RPB];
    const int t  = threadIdx.x;
    const int r0 = blockIdx.x * RPB;
    const int r1 = min(r0 + RPB, n_nodes);
    const int nr = r1 - r0;
    if (t < nr) sb[t] = batch[r0 + t];
    __syncthreads();

    const int w    = t >> 6;   // wave id 0..3
    const int lane = t & 63;

    float4 acc = make_float4(0.f, 0.f, 0.f, 0.f);
    int cur = -1;
    int runlen = 0;

    for (int i = w; i < nr; i += 4) {
        const int r = r0 + i;
        const int b = sb[i];                       // wave-uniform (LDS broadcast)
        const float4 v = hv4[(size_t)r * (HIDDEN / 4) + lane];
        if (b != cur) {                            // wave-uniform branch
            if (cur >= 0) {
                float* s = &sums[(size_t)cur * HIDDEN + lane * 4];
                atomicAdd(s + 0, acc.x); atomicAdd(s + 1, acc.y);
                atomicAdd(s + 2, acc.z); atomicAdd(s + 3, acc.w);
                if (lane == 0) atomicAdd(&counts[cur], (float)runlen);
            }
            acc = v; cur = b; runlen = 1;
        } else {
            acc.x += v.x; acc.y += v.y; acc.z += v.z; acc.w += v.w;
            ++runlen;
        }
    }
    if (cur >= 0) {
        float* s = &sums[(size_t)cur * HIDDEN + lane * 4];
        atomicAdd(s + 0, acc.x); atomicAdd(s + 1, acc.y);
        atomicAdd(s + 2, acc.z); atomicAdd(s + 3, acc.w);
        if (lane == 0) atomicAdd(&counts[cur], (float)runlen);
    }
}

// ---------------------------------------------------------------------------
// Fused 3-layer MLP. Block = 256 threads handles GT=8 graphs.
// Thread t owns output column t of each dense layer; W-column reads are
// coalesced across threads and reused for all 8 graphs (W1/W2 are L2-resident).
// ---------------------------------------------------------------------------
__global__ __launch_bounds__(256) void mlp_kernel(
    const float* __restrict__ sums, const float* __restrict__ counts,
    const float* __restrict__ W1, const float* __restrict__ b1,
    const float* __restrict__ W2, const float* __restrict__ b2,
    const float* __restrict__ W3, const float* __restrict__ b3,
    float* __restrict__ out, int n_graphs)
{
    __shared__ float xa[GT][HIDDEN];
    __shared__ float xb[GT][HIDDEN];
    const int t  = threadIdx.x;
    const int g0 = blockIdx.x * GT;

    // pooled = sums / max(counts, 1)
    #pragma unroll
    for (int g = 0; g < GT; ++g) {
        const int gg = g0 + g;
        float c = (gg < n_graphs) ? counts[gg] : 0.f;
        float s = (gg < n_graphs) ? sums[(size_t)gg * HIDDEN + t] : 0.f;
        xa[g][t] = s / fmaxf(c, 1.f);
    }
    __syncthreads();

    float acc[GT];

    // layer 1: xb = relu(xa @ W1 + b1)
    #pragma unroll
    for (int g = 0; g < GT; ++g) acc[g] = b1[t];
    for (int k = 0; k < HIDDEN; ++k) {
        const float wv = W1[k * HIDDEN + t];
        #pragma unroll
        for (int g = 0; g < GT; ++g) acc[g] = fmaf(xa[g][k], wv, acc[g]);
    }
    #pragma unroll
    for (int g = 0; g < GT; ++g) xb[g][t] = fmaxf(acc[g], 0.f);
    __syncthreads();

    // layer 2: xa = relu(xb @ W2 + b2)
    #pragma unroll
    for (int g = 0; g < GT; ++g) acc[g] = b2[t];
    for (int k = 0; k < HIDDEN; ++k) {
        const float wv = W2[k * HIDDEN + t];
        #pragma unroll
        for (int g = 0; g < GT; ++g) acc[g] = fmaf(xb[g][k], wv, acc[g]);
    }
    __syncthreads();                 // all reads of xb done before overwrite below
    #pragma unroll
    for (int g = 0; g < GT; ++g) xa[g][t] = fmaxf(acc[g], 0.f);
    __syncthreads();

    // layer 3: out[g] = b3 + xa[g] . W3   (partial products in LDS, serial tiny reduce)
    const float w3 = W3[t];
    #pragma unroll
    for (int g = 0; g < GT; ++g) xb[g][t] = xa[g][t] * w3;
    __syncthreads();

    if (t < GT) {
        const int gg = g0 + t;
        if (gg < n_graphs) {
            float s = b3[0];
            for (int k = 0; k < HIDDEN; ++k) s += xb[t][k];
            const float c = counts[gg];
            out[gg] = (c > 0.f) ? s : 0.f;
        }
    }
}

extern "C" void kernel_launch(void* const* d_in, const int* in_sizes, int n_in,
                              void* d_out, int out_size, void* d_ws, size_t ws_size,
                              hipStream_t stream) {
    const float* h_v  = (const float*)d_in[0];
    // d_in[1] = edge_index (unused by reference)
    const int*   batch = (const int*)d_in[2];
    const float* W1 = (const float*)d_in[3];
    const float* b1 = (const float*)d_in[4];
    const float* W2 = (const float*)d_in[5];
    const float* b2 = (const float*)d_in[6];
    const float* W3 = (const float*)d_in[7];
    const float* b3 = (const float*)d_in[8];
    float* out = (float*)d_out;

    const int n_nodes  = in_sizes[2];        // batch vector length
    const int n_graphs = out_size;           // OUT_DIM == 1

    float* sums   = (float*)d_ws;
    float* counts = sums + (size_t)n_graphs * HIDDEN;

    // zero accumulators every call (atomics accumulate; capture-safe memset node)
    hipMemsetAsync(d_ws, 0, ((size_t)n_graphs * HIDDEN + (size_t)n_graphs) * sizeof(float), stream);

    dim3 blk(256);
    const int nblocks = (n_nodes + RPB - 1) / RPB;
    seg_sum_kernel<<<nblocks, blk, 0, stream>>>(
        (const float4*)h_v, batch, sums, counts, n_nodes);

    const int mblocks = (n_graphs + GT - 1) / GT;
    mlp_kernel<<<mblocks, blk, 0, stream>>>(
        sums, counts, W1, b1, W2, b2, W3, b3, out, n_graphs);
}

// Round 4
// 187.758 us; speedup vs baseline: 1.0068x; 1.0068x over previous
//
#include <hip/hip_runtime.h>

#define HIDDEN 256
#define RPB 256      // rows (nodes) per block in segment-sum
#define GT 8         // graphs per block in MLP

// ---------------------------------------------------------------------------
// Workspace zero: grid-strided float4 fill. Replaces hipMemsetAsync, whose
// rocclr fill kernel ran at 6.8 GB/s (~300 us for 2.1 MB) in round-3 profile.
// ---------------------------------------------------------------------------
__global__ __launch_bounds__(256) void zero_ws_kernel(float4* __restrict__ p, int n4)
{
    int i = blockIdx.x * blockDim.x + threadIdx.x;
    if (i < n4) p[i] = make_float4(0.f, 0.f, 0.f, 0.f);
}

// ---------------------------------------------------------------------------
// Segment sum over sorted batch ids.
// Block = 256 threads = 4 waves. Wave w handles rows r0+w, r0+w+4, ...
// Each lane owns 4 consecutive hidden dims (float4, 16B/lane coalesced).
// Since batch is sorted, each wave keeps a running float4 accumulator and
// flushes with atomicAdd only when the segment id changes (~2 flushes/block).
// ---------------------------------------------------------------------------
__global__ __launch_bounds__(256) void seg_sum_kernel(
    const float4* __restrict__ hv4, const int* __restrict__ batch,
    float* __restrict__ sums, float* __restrict__ counts, int n_nodes)
{
    __shared__ int sb[RPB];
    const int t  = threadIdx.x;
    const int r0 = blockIdx.x * RPB;
    const int r1 = min(r0 + RPB, n_nodes);
    const int nr = r1 - r0;
    if (t < nr) sb[t] = batch[r0 + t];
    __syncthreads();

    const int w    = t >> 6;   // wave id 0..3
    const int lane = t & 63;

    float4 acc = make_float4(0.f, 0.f, 0.f, 0.f);
    int cur = -1;
    int runlen = 0;

    for (int i = w; i < nr; i += 4) {
        const int r = r0 + i;
        const int b = sb[i];                       // wave-uniform (LDS broadcast)
        const float4 v = hv4[(size_t)r * (HIDDEN / 4) + lane];
        if (b != cur) {                            // wave-uniform branch
            if (cur >= 0) {
                float* s = &sums[(size_t)cur * HIDDEN + lane * 4];
                atomicAdd(s + 0, acc.x); atomicAdd(s + 1, acc.y);
                atomicAdd(s + 2, acc.z); atomicAdd(s + 3, acc.w);
                if (lane == 0) atomicAdd(&counts[cur], (float)runlen);
            }
            acc = v; cur = b; runlen = 1;
        } else {
            acc.x += v.x; acc.y += v.y; acc.z += v.z; acc.w += v.w;
            ++runlen;
        }
    }
    if (cur >= 0) {
        float* s = &sums[(size_t)cur * HIDDEN + lane * 4];
        atomicAdd(s + 0, acc.x); atomicAdd(s + 1, acc.y);
        atomicAdd(s + 2, acc.z); atomicAdd(s + 3, acc.w);
        if (lane == 0) atomicAdd(&counts[cur], (float)runlen);
    }
}

// ---------------------------------------------------------------------------
// Fused 3-layer MLP. Block = 256 threads handles GT=8 graphs.
// Thread t owns output column t of each dense layer; W-column reads are
// coalesced across threads and reused for all 8 graphs (W1/W2 are L2-resident).
// ---------------------------------------------------------------------------
__global__ __launch_bounds__(256) void mlp_kernel(
    const float* __restrict__ sums, const float* __restrict__ counts,
    const float* __restrict__ W1, const float* __restrict__ b1,
    const float* __restrict__ W2, const float* __restrict__ b2,
    const float* __restrict__ W3, const float* __restrict__ b3,
    float* __restrict__ out, int n_graphs)
{
    __shared__ float xa[GT][HIDDEN];
    __shared__ float xb[GT][HIDDEN];
    const int t  = threadIdx.x;
    const int g0 = blockIdx.x * GT;

    // pooled = sums / max(counts, 1)
    #pragma unroll
    for (int g = 0; g < GT; ++g) {
        const int gg = g0 + g;
        float c = (gg < n_graphs) ? counts[gg] : 0.f;
        float s = (gg < n_graphs) ? sums[(size_t)gg * HIDDEN + t] : 0.f;
        xa[g][t] = s / fmaxf(c, 1.f);
    }
    __syncthreads();

    float acc[GT];

    // layer 1: xb = relu(xa @ W1 + b1)
    #pragma unroll
    for (int g = 0; g < GT; ++g) acc[g] = b1[t];
    for (int k = 0; k < HIDDEN; ++k) {
        const float wv = W1[k * HIDDEN + t];
        #pragma unroll
        for (int g = 0; g < GT; ++g) acc[g] = fmaf(xa[g][k], wv, acc[g]);
    }
    #pragma unroll
    for (int g = 0; g < GT; ++g) xb[g][t] = fmaxf(acc[g], 0.f);
    __syncthreads();

    // layer 2: xa = relu(xb @ W2 + b2)
    #pragma unroll
    for (int g = 0; g < GT; ++g) acc[g] = b2[t];
    for (int k = 0; k < HIDDEN; ++k) {
        const float wv = W2[k * HIDDEN + t];
        #pragma unroll
        for (int g = 0; g < GT; ++g) acc[g] = fmaf(xb[g][k], wv, acc[g]);
    }
    __syncthreads();                 // all reads of xb done before overwrite below
    #pragma unroll
    for (int g = 0; g < GT; ++g) xa[g][t] = fmaxf(acc[g], 0.f);
    __syncthreads();

    // layer 3: out[g] = b3 + xa[g] . W3   (partial products in LDS, serial tiny reduce)
    const float w3 = W3[t];
    #pragma unroll
    for (int g = 0; g < GT; ++g) xb[g][t] = xa[g][t] * w3;
    __syncthreads();

    if (t < GT) {
        const int gg = g0 + t;
        if (gg < n_graphs) {
            float s = b3[0];
            for (int k = 0; k < HIDDEN; ++k) s += xb[t][k];
            const float c = counts[gg];
            out[gg] = (c > 0.f) ? s : 0.f;
        }
    }
}

extern "C" void kernel_launch(void* const* d_in, const int* in_sizes, int n_in,
                              void* d_out, int out_size, void* d_ws, size_t ws_size,
                              hipStream_t stream) {
    const float* h_v  = (const float*)d_in[0];
    // d_in[1] = edge_index (unused by reference)
    const int*   batch = (const int*)d_in[2];
    const float* W1 = (const float*)d_in[3];
    const float* b1 = (const float*)d_in[4];
    const float* W2 = (const float*)d_in[5];
    const float* b2 = (const float*)d_in[6];
    const float* W3 = (const float*)d_in[7];
    const float* b3 = (const float*)d_in[8];
    float* out = (float*)d_out;

    const int n_nodes  = in_sizes[2];        // batch vector length
    const int n_graphs = out_size;           // OUT_DIM == 1

    float* sums   = (float*)d_ws;
    float* counts = sums + (size_t)n_graphs * HIDDEN;

    // zero accumulators every call with our own kernel (rocclr small-fill is ~300us)
    const int n_ws_floats = n_graphs * HIDDEN + n_graphs;   // 526,336 (divisible by 4)
    const int n4 = (n_ws_floats + 3) / 4;
    zero_ws_kernel<<<(n4 + 255) / 256, 256, 0, stream>>>((float4*)d_ws, n4);

    dim3 blk(256);
    const int nblocks = (n_nodes + RPB - 1) / RPB;
    seg_sum_kernel<<<nblocks, blk, 0, stream>>>(
        (const float4*)h_v, batch, sums, counts, n_nodes);

    const int mblocks = (n_graphs + GT - 1) / GT;
    mlp_kernel<<<mblocks, blk, 0, stream>>>(
        sums, counts, W1, b1, W2, b2, W3, b3, out, n_graphs);
}

// Round 5
// 161.648 us; speedup vs baseline: 1.1694x; 1.1615x over previous
//
#include <hip/hip_runtime.h>

#define HIDDEN 256
#define GT 8         // graphs per block in MLP

// lower_bound over sorted int array
__device__ __forceinline__ int lower_bound_i(const int* __restrict__ a, int n, int v)
{
    int lo = 0, hi = n;
    while (lo < hi) {
        int mid = (lo + hi) >> 1;
        if (a[mid] < v) lo = mid + 1; else hi = mid;
    }
    return lo;
}

// ---------------------------------------------------------------------------
// Segment sum, one block per graph (batch is sorted, every id present).
// Block = 256 threads = 4 waves. Each lane owns 4 consecutive hidden dims
// (float4). Wave w accumulates rows start+w, start+w+4, ... with a 4-deep
// unrolled, branch-free loop (4 independent accumulators -> >=4 loads in
// flight per wave). Cross-wave reduce via LDS, direct store (no atomics,
// no pre-zeroing of the workspace needed).
// ---------------------------------------------------------------------------
__global__ __launch_bounds__(256) void seg_sum_kernel(
    const float4* __restrict__ hv4, const int* __restrict__ batch,
    float4* __restrict__ sums4, float* __restrict__ counts,
    int n_nodes, int n_graphs)
{
    const int g    = blockIdx.x;
    const int t    = threadIdx.x;
    const int w    = t >> 6;     // wave 0..3
    const int lane = t & 63;

    // segment bounds (wave-uniform; redundant per-thread, all cached)
    const int start = lower_bound_i(batch, n_nodes, g);
    const int end   = (g + 1 < n_graphs) ? lower_bound_i(batch, n_nodes, g + 1)
                                         : n_nodes;

    float4 a0 = make_float4(0.f, 0.f, 0.f, 0.f);
    float4 a1 = make_float4(0.f, 0.f, 0.f, 0.f);
    float4 a2 = make_float4(0.f, 0.f, 0.f, 0.f);
    float4 a3 = make_float4(0.f, 0.f, 0.f, 0.f);

    int i = start + w;
    // 4 rows per wave-iteration (strided by 4 waves): rows i, i+4, i+8, i+12
    for (; i + 12 < end; i += 16) {
        const float4 v0 = hv4[(size_t)(i     ) * (HIDDEN / 4) + lane];
        const float4 v1 = hv4[(size_t)(i +  4) * (HIDDEN / 4) + lane];
        const float4 v2 = hv4[(size_t)(i +  8) * (HIDDEN / 4) + lane];
        const float4 v3 = hv4[(size_t)(i + 12) * (HIDDEN / 4) + lane];
        a0.x += v0.x; a0.y += v0.y; a0.z += v0.z; a0.w += v0.w;
        a1.x += v1.x; a1.y += v1.y; a1.z += v1.z; a1.w += v1.w;
        a2.x += v2.x; a2.y += v2.y; a2.z += v2.z; a2.w += v2.w;
        a3.x += v3.x; a3.y += v3.y; a3.z += v3.z; a3.w += v3.w;
    }
    for (; i < end; i += 4) {
        const float4 v = hv4[(size_t)i * (HIDDEN / 4) + lane];
        a0.x += v.x; a0.y += v.y; a0.z += v.z; a0.w += v.w;
    }
    a0.x += a1.x + a2.x + a3.x;
    a0.y += a1.y + a2.y + a3.y;
    a0.z += a1.z + a2.z + a3.z;
    a0.w += a1.w + a2.w + a3.w;

    __shared__ float4 part[4][64];
    part[w][lane] = a0;
    __syncthreads();

    if (w == 0) {
        const float4 p0 = part[0][lane], p1 = part[1][lane],
                     p2 = part[2][lane], p3 = part[3][lane];
        float4 s;
        s.x = p0.x + p1.x + p2.x + p3.x;
        s.y = p0.y + p1.y + p2.y + p3.y;
        s.z = p0.z + p1.z + p2.z + p3.z;
        s.w = p0.w + p1.w + p2.w + p3.w;
        sums4[(size_t)g * (HIDDEN / 4) + lane] = s;
        if (lane == 0) counts[g] = (float)(end - start);
    }
}

// ---------------------------------------------------------------------------
// Fused 3-layer MLP. Block = 256 threads handles GT=8 graphs.
// Thread t owns output column t of each dense layer; W-column reads are
// coalesced across threads and reused for all 8 graphs (W1/W2 are L2-resident).
// ---------------------------------------------------------------------------
__global__ __launch_bounds__(256) void mlp_kernel(
    const float* __restrict__ sums, const float* __restrict__ counts,
    const float* __restrict__ W1, const float* __restrict__ b1,
    const float* __restrict__ W2, const float* __restrict__ b2,
    const float* __restrict__ W3, const float* __restrict__ b3,
    float* __restrict__ out, int n_graphs)
{
    __shared__ float xa[GT][HIDDEN];
    __shared__ float xb[GT][HIDDEN];
    const int t  = threadIdx.x;
    const int g0 = blockIdx.x * GT;

    // pooled = sums / max(counts, 1)
    #pragma unroll
    for (int g = 0; g < GT; ++g) {
        const int gg = g0 + g;
        float c = (gg < n_graphs) ? counts[gg] : 0.f;
        float s = (gg < n_graphs) ? sums[(size_t)gg * HIDDEN + t] : 0.f;
        xa[g][t] = s / fmaxf(c, 1.f);
    }
    __syncthreads();

    float acc[GT];

    // layer 1: xb = relu(xa @ W1 + b1)
    #pragma unroll
    for (int g = 0; g < GT; ++g) acc[g] = b1[t];
    for (int k = 0; k < HIDDEN; ++k) {
        const float wv = W1[k * HIDDEN + t];
        #pragma unroll
        for (int g = 0; g < GT; ++g) acc[g] = fmaf(xa[g][k], wv, acc[g]);
    }
    #pragma unroll
    for (int g = 0; g < GT; ++g) xb[g][t] = fmaxf(acc[g], 0.f);
    __syncthreads();

    // layer 2: xa = relu(xb @ W2 + b2)
    #pragma unroll
    for (int g = 0; g < GT; ++g) acc[g] = b2[t];
    for (int k = 0; k < HIDDEN; ++k) {
        const float wv = W2[k * HIDDEN + t];
        #pragma unroll
        for (int g = 0; g < GT; ++g) acc[g] = fmaf(xb[g][k], wv, acc[g]);
    }
    __syncthreads();                 // all reads of xb done before overwrite below
    #pragma unroll
    for (int g = 0; g < GT; ++g) xa[g][t] = fmaxf(acc[g], 0.f);
    __syncthreads();

    // layer 3: out[g] = b3 + xa[g] . W3   (partial products in LDS, serial tiny reduce)
    const float w3 = W3[t];
    #pragma unroll
    for (int g = 0; g < GT; ++g) xb[g][t] = xa[g][t] * w3;
    __syncthreads();

    if (t < GT) {
        const int gg = g0 + t;
        if (gg < n_graphs) {
            float s = b3[0];
            for (int k = 0; k < HIDDEN; ++k) s += xb[t][k];
            const float c = counts[gg];
            out[gg] = (c > 0.f) ? s : 0.f;
        }
    }
}

extern "C" void kernel_launch(void* const* d_in, const int* in_sizes, int n_in,
                              void* d_out, int out_size, void* d_ws, size_t ws_size,
                              hipStream_t stream) {
    const float* h_v  = (const float*)d_in[0];
    // d_in[1] = edge_index (unused by reference)
    const int*   batch = (const int*)d_in[2];
    const float* W1 = (const float*)d_in[3];
    const float* b1 = (const float*)d_in[4];
    const float* W2 = (const float*)d_in[5];
    const float* b2 = (const float*)d_in[6];
    const float* W3 = (const float*)d_in[7];
    const float* b3 = (const float*)d_in[8];
    float* out = (float*)d_out;

    const int n_nodes  = in_sizes[2];        // batch vector length
    const int n_graphs = out_size;           // OUT_DIM == 1

    float* sums   = (float*)d_ws;
    float* counts = sums + (size_t)n_graphs * HIDDEN;

    dim3 blk(256);
    seg_sum_kernel<<<n_graphs, blk, 0, stream>>>(
        (const float4*)h_v, batch, (float4*)sums, counts, n_nodes, n_graphs);

    const int mblocks = (n_graphs + GT - 1) / GT;
    mlp_kernel<<<mblocks, blk, 0, stream>>>(
        sums, counts, W1, b1, W2, b2, W3, b3, out, n_graphs);
}

// Round 6
// 127.944 us; speedup vs baseline: 1.4774x; 1.2634x over previous
//
#include <hip/hip_runtime.h>

#define HIDDEN 256

// lower_bound over sorted int array
__device__ __forceinline__ int lower_bound_i(const int* __restrict__ a, int n, int v)
{
    int lo = 0, hi = n;
    while (lo < hi) {
        int mid = (lo + hi) >> 1;
        if (a[mid] < v) lo = mid + 1; else hi = mid;
    }
    return lo;
}

// ---------------------------------------------------------------------------
// Fully fused: one block per graph (batch sorted, ids 0..G-1).
// Phase 1: stream segment rows, 4 waves x 4-deep float4 accumulate.
// Phase 2: LDS reduce -> pooled vector xs[256] (divided by count).
// Phase 3: 3-layer MLP for this graph; thread t owns hidden column t,
//          k-loop unrolled x8 with register-prefetched W columns (L2-hit).
// MLP latency hides under other resident blocks' HBM streaming.
// ---------------------------------------------------------------------------
__global__ __launch_bounds__(256) void fused_readout_kernel(
    const float4* __restrict__ hv4, const int* __restrict__ batch,
    const float* __restrict__ W1, const float* __restrict__ b1,
    const float* __restrict__ W2, const float* __restrict__ b2,
    const float* __restrict__ W3, const float* __restrict__ b3,
    float* __restrict__ out, int n_nodes, int n_graphs)
{
    const int g    = blockIdx.x;
    const int t    = threadIdx.x;
    const int w    = t >> 6;     // wave 0..3
    const int lane = t & 63;

    // segment bounds (uniform within block; redundant per-thread, cached)
    const int start = lower_bound_i(batch, n_nodes, g);
    const int end   = (g + 1 < n_graphs) ? lower_bound_i(batch, n_nodes, g + 1)
                                         : n_nodes;
    const int cnt = end - start;

    // ---- phase 1: stream rows ------------------------------------------
    float4 a0 = make_float4(0.f, 0.f, 0.f, 0.f);
    float4 a1 = make_float4(0.f, 0.f, 0.f, 0.f);
    float4 a2 = make_float4(0.f, 0.f, 0.f, 0.f);
    float4 a3 = make_float4(0.f, 0.f, 0.f, 0.f);

    int i = start + w;
    for (; i + 12 < end; i += 16) {          // rows i, i+4, i+8, i+12 for wave w
        const float4 v0 = hv4[(size_t)(i     ) * (HIDDEN / 4) + lane];
        const float4 v1 = hv4[(size_t)(i +  4) * (HIDDEN / 4) + lane];
        const float4 v2 = hv4[(size_t)(i +  8) * (HIDDEN / 4) + lane];
        const float4 v3 = hv4[(size_t)(i + 12) * (HIDDEN / 4) + lane];
        a0.x += v0.x; a0.y += v0.y; a0.z += v0.z; a0.w += v0.w;
        a1.x += v1.x; a1.y += v1.y; a1.z += v1.z; a1.w += v1.w;
        a2.x += v2.x; a2.y += v2.y; a2.z += v2.z; a2.w += v2.w;
        a3.x += v3.x; a3.y += v3.y; a3.z += v3.z; a3.w += v3.w;
    }
    for (; i < end; i += 4) {
        const float4 v = hv4[(size_t)i * (HIDDEN / 4) + lane];
        a0.x += v.x; a0.y += v.y; a0.z += v.z; a0.w += v.w;
    }
    a0.x += a1.x + a2.x + a3.x;
    a0.y += a1.y + a2.y + a3.y;
    a0.z += a1.z + a2.z + a3.z;
    a0.w += a1.w + a2.w + a3.w;

    // ---- phase 2: cross-wave reduce -> pooled vector in LDS -------------
    __shared__ float4 part[4][64];           // 4 KB
    __shared__ float  xs[HIDDEN];            // pooled / layer-1 input
    __shared__ float  ys[HIDDEN];            // layer-2 input / final products
    part[w][lane] = a0;
    __syncthreads();

    if (w == 0) {
        const float4 p0 = part[0][lane], p1 = part[1][lane],
                     p2 = part[2][lane], p3 = part[3][lane];
        const float inv = 1.0f / fmaxf((float)cnt, 1.0f);
        float4 s;
        s.x = (p0.x + p1.x + p2.x + p3.x) * inv;
        s.y = (p0.y + p1.y + p2.y + p3.y) * inv;
        s.z = (p0.z + p1.z + p2.z + p3.z) * inv;
        s.w = (p0.w + p1.w + p2.w + p3.w) * inv;
        ((float4*)xs)[lane] = s;
    }
    __syncthreads();

    // ---- phase 3: MLP (thread t owns column t) --------------------------
    // layer 1: ys[t] = relu(b1[t] + sum_k xs[k]*W1[k][t])
    {
        float acc = b1[t];
        #pragma unroll 1
        for (int k = 0; k < HIDDEN; k += 8) {
            const float w0 = W1[(k + 0) * HIDDEN + t];
            const float w1_ = W1[(k + 1) * HIDDEN + t];
            const float w2_ = W1[(k + 2) * HIDDEN + t];
            const float w3_ = W1[(k + 3) * HIDDEN + t];
            const float w4 = W1[(k + 4) * HIDDEN + t];
            const float w5 = W1[(k + 5) * HIDDEN + t];
            const float w6 = W1[(k + 6) * HIDDEN + t];
            const float w7 = W1[(k + 7) * HIDDEN + t];
            acc = fmaf(xs[k + 0], w0, acc);
            acc = fmaf(xs[k + 1], w1_, acc);
            acc = fmaf(xs[k + 2], w2_, acc);
            acc = fmaf(xs[k + 3], w3_, acc);
            acc = fmaf(xs[k + 4], w4, acc);
            acc = fmaf(xs[k + 5], w5, acc);
            acc = fmaf(xs[k + 6], w6, acc);
            acc = fmaf(xs[k + 7], w7, acc);
        }
        ys[t] = fmaxf(acc, 0.f);
    }
    __syncthreads();

    // layer 2: xs[t] = relu(b2[t] + sum_k ys[k]*W2[k][t])  (xs reuse is safe:
    // all lanes finished reading xs before the barrier above... NOT true —
    // barrier above guarantees it: every thread read xs only before writing ys.)
    float l2acc;
    {
        float acc = b2[t];
        #pragma unroll 1
        for (int k = 0; k < HIDDEN; k += 8) {
            const float w0 = W2[(k + 0) * HIDDEN + t];
            const float w1_ = W2[(k + 1) * HIDDEN + t];
            const float w2_ = W2[(k + 2) * HIDDEN + t];
            const float w3_ = W2[(k + 3) * HIDDEN + t];
            const float w4 = W2[(k + 4) * HIDDEN + t];
            const float w5 = W2[(k + 5) * HIDDEN + t];
            const float w6 = W2[(k + 6) * HIDDEN + t];
            const float w7 = W2[(k + 7) * HIDDEN + t];
            acc = fmaf(ys[k + 0], w0, acc);
            acc = fmaf(ys[k + 1], w1_, acc);
            acc = fmaf(ys[k + 2], w2_, acc);
            acc = fmaf(ys[k + 3], w3_, acc);
            acc = fmaf(ys[k + 4], w4, acc);
            acc = fmaf(ys[k + 5], w5, acc);
            acc = fmaf(ys[k + 6], w6, acc);
            acc = fmaf(ys[k + 7], w7, acc);
        }
        l2acc = fmaxf(acc, 0.f);
    }
    __syncthreads();                          // ys reads done before overwrite

    // layer 3: out[g] = b3 + sum_t l2acc[t]*W3[t]
    ys[t] = l2acc * W3[t];
    __syncthreads();

    if (w == 0) {
        float s = ys[lane] + ys[64 + lane] + ys[128 + lane] + ys[192 + lane];
        #pragma unroll
        for (int off = 32; off > 0; off >>= 1)
            s += __shfl_down(s, off, 64);
        if (lane == 0)
            out[g] = (cnt > 0) ? (s + b3[0]) : 0.f;
    }
}

extern "C" void kernel_launch(void* const* d_in, const int* in_sizes, int n_in,
                              void* d_out, int out_size, void* d_ws, size_t ws_size,
                              hipStream_t stream) {
    const float* h_v  = (const float*)d_in[0];
    // d_in[1] = edge_index (unused by reference)
    const int*   batch = (const int*)d_in[2];
    const float* W1 = (const float*)d_in[3];
    const float* b1 = (const float*)d_in[4];
    const float* W2 = (const float*)d_in[5];
    const float* b2 = (const float*)d_in[6];
    const float* W3 = (const float*)d_in[7];
    const float* b3 = (const float*)d_in[8];
    float* out = (float*)d_out;

    const int n_nodes  = in_sizes[2];        // batch vector length
    const int n_graphs = out_size;           // OUT_DIM == 1

    fused_readout_kernel<<<n_graphs, 256, 0, stream>>>(
        (const float4*)h_v, batch, W1, b1, W2, b2, W3, b3,
        out, n_nodes, n_graphs);
}

// Round 7
// 118.129 us; speedup vs baseline: 1.6002x; 1.0831x over previous
//
#include <hip/hip_runtime.h>

#define HIDDEN 256
#define GPB 4        // graphs per block; one wave per graph

// lower_bound over sorted int array
__device__ __forceinline__ int lower_bound_i(const int* __restrict__ a, int n, int v)
{
    int lo = 0, hi = n;
    while (lo < hi) {
        int mid = (lo + hi) >> 1;
        if (a[mid] < v) lo = mid + 1; else hi = mid;
    }
    return lo;
}

// ---------------------------------------------------------------------------
// Fused readout, 4 graphs per block, one wave per graph.
// Phase 1: wave w streams graph (blockIdx*4+w)'s rows CONTIGUOUSLY with an
//          8-deep float4 load pipeline (lane owns 4 hidden dims; one wave
//          load = one full 1KB row). No cross-wave reduce needed.
// Phase 2: pooled vectors (already /count) to LDS.
// Phase 3: 3-layer MLP; thread t owns column t, acc[4] for the block's 4
//          graphs ->每 W element loaded once per block (4x reuse), 256 MB
//          aggregate L2 traffic instead of 1 GB.
// ---------------------------------------------------------------------------
__global__ __launch_bounds__(256) void fused_readout_kernel(
    const float4* __restrict__ hv4, const int* __restrict__ batch,
    const float* __restrict__ W1, const float* __restrict__ b1,
    const float* __restrict__ W2, const float* __restrict__ b2,
    const float* __restrict__ W3, const float* __restrict__ b3,
    float* __restrict__ out, int n_nodes, int n_graphs)
{
    const int t    = threadIdx.x;
    const int w    = t >> 6;     // wave 0..3
    const int lane = t & 63;
    const int g    = blockIdx.x * GPB + w;   // this wave's graph

    __shared__ float xs[GPB][HIDDEN];   // pooled -> layer2 output
    __shared__ float ys[GPB][HIDDEN];   // layer1 output -> layer3 products
    __shared__ float scnt[GPB];

    // ---- phase 1: bounds + contiguous stream (wave-uniform control) -----
    int start = 0, end = 0;
    if (g < n_graphs) {
        start = lower_bound_i(batch, n_nodes, g);
        end   = (g + 1 < n_graphs) ? lower_bound_i(batch, n_nodes, g + 1)
                                   : n_nodes;
    }
    const int cnt = end - start;

    float4 a0 = make_float4(0.f, 0.f, 0.f, 0.f);
    float4 a1 = make_float4(0.f, 0.f, 0.f, 0.f);
    float4 a2 = make_float4(0.f, 0.f, 0.f, 0.f);
    float4 a3 = make_float4(0.f, 0.f, 0.f, 0.f);

    const float4* p = hv4 + (size_t)start * (HIDDEN / 4) + lane;
    int i = 0;
    for (; i + 8 <= cnt; i += 8) {       // 8 rows, 8 loads in flight
        const float4 v0 = p[(size_t)(i + 0) * (HIDDEN / 4)];
        const float4 v1 = p[(size_t)(i + 1) * (HIDDEN / 4)];
        const float4 v2 = p[(size_t)(i + 2) * (HIDDEN / 4)];
        const float4 v3 = p[(size_t)(i + 3) * (HIDDEN / 4)];
        const float4 v4 = p[(size_t)(i + 4) * (HIDDEN / 4)];
        const float4 v5 = p[(size_t)(i + 5) * (HIDDEN / 4)];
        const float4 v6 = p[(size_t)(i + 6) * (HIDDEN / 4)];
        const float4 v7 = p[(size_t)(i + 7) * (HIDDEN / 4)];
        a0.x += v0.x; a0.y += v0.y; a0.z += v0.z; a0.w += v0.w;
        a1.x += v1.x; a1.y += v1.y; a1.z += v1.z; a1.w += v1.w;
        a2.x += v2.x; a2.y += v2.y; a2.z += v2.z; a2.w += v2.w;
        a3.x += v3.x; a3.y += v3.y; a3.z += v3.z; a3.w += v3.w;
        a0.x += v4.x; a0.y += v4.y; a0.z += v4.z; a0.w += v4.w;
        a1.x += v5.x; a1.y += v5.y; a1.z += v5.z; a1.w += v5.w;
        a2.x += v6.x; a2.y += v6.y; a2.z += v6.z; a2.w += v6.w;
        a3.x += v7.x; a3.y += v7.y; a3.z += v7.z; a3.w += v7.w;
    }
    for (; i < cnt; ++i) {
        const float4 v = p[(size_t)i * (HIDDEN / 4)];
        a0.x += v.x; a0.y += v.y; a0.z += v.z; a0.w += v.w;
    }

    // ---- phase 2: pooled vector to LDS ----------------------------------
    const float inv = 1.0f / fmaxf((float)cnt, 1.0f);
    float4 s;
    s.x = (a0.x + a1.x + a2.x + a3.x) * inv;
    s.y = (a0.y + a1.y + a2.y + a3.y) * inv;
    s.z = (a0.z + a1.z + a2.z + a3.z) * inv;
    s.w = (a0.w + a1.w + a2.w + a3.w) * inv;
    if (g < n_graphs) {
        ((float4*)xs[w])[lane] = s;
        if (lane == 0) scnt[w] = (float)cnt;
    } else if (lane == 0) {
        scnt[w] = 0.f;
    }
    __syncthreads();

    // ---- phase 3: MLP, thread t owns column t, 4 graphs per thread ------
    float acc0, acc1, acc2, acc3;

    // layer 1: ys = relu(xs @ W1 + b1)
    acc0 = acc1 = acc2 = acc3 = b1[t];
    for (int k = 0; k < HIDDEN; k += 8) {
        const float w0 = W1[(k + 0) * HIDDEN + t];
        const float w1_ = W1[(k + 1) * HIDDEN + t];
        const float w2_ = W1[(k + 2) * HIDDEN + t];
        const float w3_ = W1[(k + 3) * HIDDEN + t];
        const float w4 = W1[(k + 4) * HIDDEN + t];
        const float w5 = W1[(k + 5) * HIDDEN + t];
        const float w6 = W1[(k + 6) * HIDDEN + t];
        const float w7 = W1[(k + 7) * HIDDEN + t];
        const float4 xA0 = *(const float4*)&xs[0][k];
        const float4 xA1 = *(const float4*)&xs[0][k + 4];
        const float4 xB0 = *(const float4*)&xs[1][k];
        const float4 xB1 = *(const float4*)&xs[1][k + 4];
        const float4 xC0 = *(const float4*)&xs[2][k];
        const float4 xC1 = *(const float4*)&xs[2][k + 4];
        const float4 xD0 = *(const float4*)&xs[3][k];
        const float4 xD1 = *(const float4*)&xs[3][k + 4];
        acc0 = fmaf(xA0.x, w0, acc0); acc0 = fmaf(xA0.y, w1_, acc0);
        acc0 = fmaf(xA0.z, w2_, acc0); acc0 = fmaf(xA0.w, w3_, acc0);
        acc0 = fmaf(xA1.x, w4, acc0); acc0 = fmaf(xA1.y, w5, acc0);
        acc0 = fmaf(xA1.z, w6, acc0); acc0 = fmaf(xA1.w, w7, acc0);
        acc1 = fmaf(xB0.x, w0, acc1); acc1 = fmaf(xB0.y, w1_, acc1);
        acc1 = fmaf(xB0.z, w2_, acc1); acc1 = fmaf(xB0.w, w3_, acc1);
        acc1 = fmaf(xB1.x, w4, acc1); acc1 = fmaf(xB1.y, w5, acc1);
        acc1 = fmaf(xB1.z, w6, acc1); acc1 = fmaf(xB1.w, w7, acc1);
        acc2 = fmaf(xC0.x, w0, acc2); acc2 = fmaf(xC0.y, w1_, acc2);
        acc2 = fmaf(xC0.z, w2_, acc2); acc2 = fmaf(xC0.w, w3_, acc2);
        acc2 = fmaf(xC1.x, w4, acc2); acc2 = fmaf(xC1.y, w5, acc2);
        acc2 = fmaf(xC1.z, w6, acc2); acc2 = fmaf(xC1.w, w7, acc2);
        acc3 = fmaf(xD0.x, w0, acc3); acc3 = fmaf(xD0.y, w1_, acc3);
        acc3 = fmaf(xD0.z, w2_, acc3); acc3 = fmaf(xD0.w, w3_, acc3);
        acc3 = fmaf(xD1.x, w4, acc3); acc3 = fmaf(xD1.y, w5, acc3);
        acc3 = fmaf(xD1.z, w6, acc3); acc3 = fmaf(xD1.w, w7, acc3);
    }
    __syncthreads();                 // xs reads done (layer-1 inputs consumed)
    ys[0][t] = fmaxf(acc0, 0.f);
    ys[1][t] = fmaxf(acc1, 0.f);
    ys[2][t] = fmaxf(acc2, 0.f);
    ys[3][t] = fmaxf(acc3, 0.f);
    __syncthreads();

    // layer 2: xs = relu(ys @ W2 + b2)
    acc0 = acc1 = acc2 = acc3 = b2[t];
    for (int k = 0; k < HIDDEN; k += 8) {
        const float w0 = W2[(k + 0) * HIDDEN + t];
        const float w1_ = W2[(k + 1) * HIDDEN + t];
        const float w2_ = W2[(k + 2) * HIDDEN + t];
        const float w3_ = W2[(k + 3) * HIDDEN + t];
        const float w4 = W2[(k + 4) * HIDDEN + t];
        const float w5 = W2[(k + 5) * HIDDEN + t];
        const float w6 = W2[(k + 6) * HIDDEN + t];
        const float w7 = W2[(k + 7) * HIDDEN + t];
        const float4 xA0 = *(const float4*)&ys[0][k];
        const float4 xA1 = *(const float4*)&ys[0][k + 4];
        const float4 xB0 = *(const float4*)&ys[1][k];
        const float4 xB1 = *(const float4*)&ys[1][k + 4];
        const float4 xC0 = *(const float4*)&ys[2][k];
        const float4 xC1 = *(const float4*)&ys[2][k + 4];
        const float4 xD0 = *(const float4*)&ys[3][k];
        const float4 xD1 = *(const float4*)&ys[3][k + 4];
        acc0 = fmaf(xA0.x, w0, acc0); acc0 = fmaf(xA0.y, w1_, acc0);
        acc0 = fmaf(xA0.z, w2_, acc0); acc0 = fmaf(xA0.w, w3_, acc0);
        acc0 = fmaf(xA1.x, w4, acc0); acc0 = fmaf(xA1.y, w5, acc0);
        acc0 = fmaf(xA1.z, w6, acc0); acc0 = fmaf(xA1.w, w7, acc0);
        acc1 = fmaf(xB0.x, w0, acc1); acc1 = fmaf(xB0.y, w1_, acc1);
        acc1 = fmaf(xB0.z, w2_, acc1); acc1 = fmaf(xB0.w, w3_, acc1);
        acc1 = fmaf(xB1.x, w4, acc1); acc1 = fmaf(xB1.y, w5, acc1);
        acc1 = fmaf(xB1.z, w6, acc1); acc1 = fmaf(xB1.w, w7, acc1);
        acc2 = fmaf(xC0.x, w0, acc2); acc2 = fmaf(xC0.y, w1_, acc2);
        acc2 = fmaf(xC0.z, w2_, acc2); acc2 = fmaf(xC0.w, w3_, acc2);
        acc2 = fmaf(xC1.x, w4, acc2); acc2 = fmaf(xC1.y, w5, acc2);
        acc2 = fmaf(xC1.z, w6, acc2); acc2 = fmaf(xC1.w, w7, acc2);
        acc3 = fmaf(xD0.x, w0, acc3); acc3 = fmaf(xD0.y, w1_, acc3);
        acc3 = fmaf(xD0.z, w2_, acc3); acc3 = fmaf(xD0.w, w3_, acc3);
        acc3 = fmaf(xD1.x, w4, acc3); acc3 = fmaf(xD1.y, w5, acc3);
        acc3 = fmaf(xD1.z, w6, acc3); acc3 = fmaf(xD1.w, w7, acc3);
    }
    __syncthreads();                 // ys reads done
    // layer 3 products: reuse ys
    const float w3v = W3[t];
    ys[0][t] = fmaxf(acc0, 0.f) * w3v;
    ys[1][t] = fmaxf(acc1, 0.f) * w3v;
    ys[2][t] = fmaxf(acc2, 0.f) * w3v;
    ys[3][t] = fmaxf(acc3, 0.f) * w3v;
    __syncthreads();

    // wave w reduces its own graph's 256 products
    if (g < n_graphs) {
        float r = ys[w][lane] + ys[w][64 + lane] + ys[w][128 + lane] + ys[w][192 + lane];
        #pragma unroll
        for (int off = 32; off > 0; off >>= 1)
            r += __shfl_down(r, off, 64);
        if (lane == 0)
            out[g] = (scnt[w] > 0.f) ? (r + b3[0]) : 0.f;
    }
}

extern "C" void kernel_launch(void* const* d_in, const int* in_sizes, int n_in,
                              void* d_out, int out_size, void* d_ws, size_t ws_size,
                              hipStream_t stream) {
    const float* h_v  = (const float*)d_in[0];
    // d_in[1] = edge_index (unused by reference)
    const int*   batch = (const int*)d_in[2];
    const float* W1 = (const float*)d_in[3];
    const float* b1 = (const float*)d_in[4];
    const float* W2 = (const float*)d_in[5];
    const float* b2 = (const float*)d_in[6];
    const float* W3 = (const float*)d_in[7];
    const float* b3 = (const float*)d_in[8];
    float* out = (float*)d_out;

    const int n_nodes  = in_sizes[2];        // batch vector length
    const int n_graphs = out_size;           // OUT_DIM == 1

    const int nblocks = (n_graphs + GPB - 1) / GPB;
    fused_readout_kernel<<<nblocks, 256, 0, stream>>>(
        (const float4*)h_v, batch, W1, b1, W2, b2, W3, b3,
        out, n_nodes, n_graphs);
}

// Round 8
// 100.983 us; speedup vs baseline: 1.8719x; 1.1698x over previous
//
#include <hip/hip_runtime.h>

#define HIDDEN 256
#define NV4 (HIDDEN / 4)
#define GPB 4        // graphs per block; 2 waves per graph, 512-thread blocks

typedef float f4 __attribute__((ext_vector_type(4)));

// lower_bound over sorted int array
__device__ __forceinline__ int lower_bound_i(const int* __restrict__ a, int n, int v)
{
    int lo = 0, hi = n;
    while (lo < hi) {
        int mid = (lo + hi) >> 1;
        if (a[mid] < v) lo = mid + 1; else hi = mid;
    }
    return lo;
}

__device__ __forceinline__ f4 ntl(const f4* p) { return __builtin_nontemporal_load(p); }

#define LOAD8(X, base) do { \
    X##0 = ntl(p + (size_t)((base) + 0) * NV4); \
    X##1 = ntl(p + (size_t)((base) + 1) * NV4); \
    X##2 = ntl(p + (size_t)((base) + 2) * NV4); \
    X##3 = ntl(p + (size_t)((base) + 3) * NV4); \
    X##4 = ntl(p + (size_t)((base) + 4) * NV4); \
    X##5 = ntl(p + (size_t)((base) + 5) * NV4); \
    X##6 = ntl(p + (size_t)((base) + 6) * NV4); \
    X##7 = ntl(p + (size_t)((base) + 7) * NV4); \
} while (0)

#define ACC8(X) do { \
    a0 += X##0; a1 += X##1; a2 += X##2; a3 += X##3; \
    a0 += X##4; a1 += X##5; a2 += X##6; a3 += X##7; \
} while (0)

// ---------------------------------------------------------------------------
// Fused readout: 512-thread blocks (8 waves), 4 graphs/block, 2 waves/graph.
// Phase 1: wave pair (2a, 2a+1) streams graph a's rows as two contiguous
//          halves with a register double-buffered (8-deep) non-temporal
//          float4 pipeline -> loads stay in flight across accumulation.
// Phase 2: pair-reduce partials in LDS -> pooled vector xs[a].
// Phase 3: MLP; threads 0-255 handle graphs 0-1, threads 256-511 graphs 2-3
//          (thread owns column t&255; W columns L2-resident, 4x block reuse).
// ---------------------------------------------------------------------------
__global__ __launch_bounds__(512, 4) void fused_readout_kernel(
    const f4* __restrict__ hv4, const int* __restrict__ batch,
    const float* __restrict__ W1, const float* __restrict__ b1,
    const float* __restrict__ W2, const float* __restrict__ b2,
    const float* __restrict__ W3, const float* __restrict__ b3,
    float* __restrict__ out, int n_nodes, int n_graphs)
{
    const int t    = threadIdx.x;
    const int w    = t >> 6;     // wave 0..7
    const int lane = t & 63;
    const int a    = w >> 1;                 // graph index in block (0..3)
    const int g    = blockIdx.x * GPB + a;   // this wave-pair's graph

    __shared__ __align__(16) f4    part[8][64];      // 8 KB partials
    __shared__ __align__(16) float xs[GPB][HIDDEN];  // pooled
    __shared__ __align__(16) float ys[GPB][HIDDEN];  // layer-1 out
    __shared__ __align__(16) float zs[GPB][HIDDEN];  // layer-3 products
    __shared__ float scnt[GPB];

    // ---- phase 1: bounds + pipelined contiguous stream ------------------
    int start = 0, end = 0;
    if (g < n_graphs) {
        start = lower_bound_i(batch, n_nodes, g);
        end   = (g + 1 < n_graphs) ? lower_bound_i(batch, n_nodes, g + 1)
                                   : n_nodes;
    }
    const int cnt  = end - start;
    const int half = (cnt + 1) >> 1;
    const int rs   = (w & 1) ? (start + half) : start;
    const int re   = (w & 1) ? end : (start + half);
    const int n    = re - rs;

    f4 a0 = (f4)0.f, a1 = (f4)0.f, a2 = (f4)0.f, a3 = (f4)0.f;
    f4 A0, A1, A2, A3, A4, A5, A6, A7;
    f4 B0, B1, B2, B3, B4, B5, B6, B7;

    const f4* p = hv4 + (size_t)rs * NV4 + lane;
    int i = 0;
    if (n >= 8) {
        LOAD8(A, 0);
        i = 8;
        for (; i + 16 <= n; i += 16) {       // steady state: 8 loads always in flight
            LOAD8(B, i);     ACC8(A);
            LOAD8(A, i + 8); ACC8(B);
        }
        if (i + 8 <= n) { LOAD8(B, i); ACC8(A); i += 8; ACC8(B); }
        else            { ACC8(A); }
    }
    for (; i < n; ++i) a0 += ntl(p + (size_t)i * NV4);

    a0 += a1; a2 += a3; a0 += a2;
    part[w][lane] = a0;
    if ((w & 1) == 0 && lane == 0) scnt[a] = (float)cnt;
    __syncthreads();

    // ---- phase 2: pair-combine -> pooled vector -------------------------
    if (t < 256) {
        const int aa = t >> 6;               // graph in block
        const f4 p0 = part[2 * aa][lane], p1 = part[2 * aa + 1][lane];
        const float inv = 1.0f / fmaxf(scnt[aa], 1.0f);
        ((f4*)xs[aa])[lane] = (p0 + p1) * inv;
    }
    __syncthreads();

    // ---- phase 3: MLP ---------------------------------------------------
    const int tl = t & 255;                  // column
    const int ga = (t >> 8) * 2;             // first of this half's 2 graphs
    const int gb = ga + 1;
    float accA, accB;

    // layer 1: ys = relu(xs @ W1 + b1)
    accA = accB = b1[tl];
    for (int k = 0; k < HIDDEN; k += 8) {
        const float w0 = W1[(k + 0) * HIDDEN + tl];
        const float w1_ = W1[(k + 1) * HIDDEN + tl];
        const float w2_ = W1[(k + 2) * HIDDEN + tl];
        const float w3_ = W1[(k + 3) * HIDDEN + tl];
        const float w4 = W1[(k + 4) * HIDDEN + tl];
        const float w5 = W1[(k + 5) * HIDDEN + tl];
        const float w6 = W1[(k + 6) * HIDDEN + tl];
        const float w7 = W1[(k + 7) * HIDDEN + tl];
        const f4 xA0 = *(const f4*)&xs[ga][k];
        const f4 xA1 = *(const f4*)&xs[ga][k + 4];
        const f4 xB0 = *(const f4*)&xs[gb][k];
        const f4 xB1 = *(const f4*)&xs[gb][k + 4];
        accA = fmaf(xA0.x, w0, accA); accA = fmaf(xA0.y, w1_, accA);
        accA = fmaf(xA0.z, w2_, accA); accA = fmaf(xA0.w, w3_, accA);
        accA = fmaf(xA1.x, w4, accA); accA = fmaf(xA1.y, w5, accA);
        accA = fmaf(xA1.z, w6, accA); accA = fmaf(xA1.w, w7, accA);
        accB = fmaf(xB0.x, w0, accB); accB = fmaf(xB0.y, w1_, accB);
        accB = fmaf(xB0.z, w2_, accB); accB = fmaf(xB0.w, w3_, accB);
        accB = fmaf(xB1.x, w4, accB); accB = fmaf(xB1.y, w5, accB);
        accB = fmaf(xB1.z, w6, accB); accB = fmaf(xB1.w, w7, accB);
    }
    ys[ga][tl] = fmaxf(accA, 0.f);
    ys[gb][tl] = fmaxf(accB, 0.f);
    __syncthreads();

    // layer 2: zs = relu(ys @ W2 + b2) * W3  (products for the final dot)
    accA = accB = b2[tl];
    for (int k = 0; k < HIDDEN; k += 8) {
        const float w0 = W2[(k + 0) * HIDDEN + tl];
        const float w1_ = W2[(k + 1) * HIDDEN + tl];
        const float w2_ = W2[(k + 2) * HIDDEN + tl];
        const float w3_ = W2[(k + 3) * HIDDEN + tl];
        const float w4 = W2[(k + 4) * HIDDEN + tl];
        const float w5 = W2[(k + 5) * HIDDEN + tl];
        const float w6 = W2[(k + 6) * HIDDEN + tl];
        const float w7 = W2[(k + 7) * HIDDEN + tl];
        const f4 xA0 = *(const f4*)&ys[ga][k];
        const f4 xA1 = *(const f4*)&ys[ga][k + 4];
        const f4 xB0 = *(const f4*)&ys[gb][k];
        const f4 xB1 = *(const f4*)&ys[gb][k + 4];
        accA = fmaf(xA0.x, w0, accA); accA = fmaf(xA0.y, w1_, accA);
        accA = fmaf(xA0.z, w2_, accA); accA = fmaf(xA0.w, w3_, accA);
        accA = fmaf(xA1.x, w4, accA); accA = fmaf(xA1.y, w5, accA);
        accA = fmaf(xA1.z, w6, accA); accA = fmaf(xA1.w, w7, accA);
        accB = fmaf(xB0.x, w0, accB); accB = fmaf(xB0.y, w1_, accB);
        accB = fmaf(xB0.z, w2_, accB); accB = fmaf(xB0.w, w3_, accB);
        accB = fmaf(xB1.x, w4, accB); accB = fmaf(xB1.y, w5, accB);
        accB = fmaf(xB1.z, w6, accB); accB = fmaf(xB1.w, w7, accB);
    }
    const float w3v = W3[tl];
    zs[ga][tl] = fmaxf(accA, 0.f) * w3v;
    zs[gb][tl] = fmaxf(accB, 0.f) * w3v;
    __syncthreads();

    // final: wave q (q<4) reduces graph q's 256 products
    if (w < 4) {
        const int gg = blockIdx.x * GPB + w;
        if (gg < n_graphs) {
            float r = zs[w][lane] + zs[w][64 + lane]
                    + zs[w][128 + lane] + zs[w][192 + lane];
            #pragma unroll
            for (int off = 32; off > 0; off >>= 1)
                r += __shfl_down(r, off, 64);
            if (lane == 0)
                out[gg] = (scnt[w] > 0.f) ? (r + b3[0]) : 0.f;
        }
    }
}

extern "C" void kernel_launch(void* const* d_in, const int* in_sizes, int n_in,
                              void* d_out, int out_size, void* d_ws, size_t ws_size,
                              hipStream_t stream) {
    const float* h_v  = (const float*)d_in[0];
    // d_in[1] = edge_index (unused by reference)
    const int*   batch = (const int*)d_in[2];
    const float* W1 = (const float*)d_in[3];
    const float* b1 = (const float*)d_in[4];
    const float* W2 = (const float*)d_in[5];
    const float* b2 = (const float*)d_in[6];
    const float* W3 = (const float*)d_in[7];
    const float* b3 = (const float*)d_in[8];
    float* out = (float*)d_out;

    const int n_nodes  = in_sizes[2];        // batch vector length
    const int n_graphs = out_size;           // OUT_DIM == 1

    const int nblocks = (n_graphs + GPB - 1) / GPB;
    fused_readout_kernel<<<nblocks, 512, 0, stream>>>(
        (const f4*)h_v, batch, W1, b1, W2, b2, W3, b3,
        out, n_nodes, n_graphs);
}